// Round 1
// baseline (285.523 us; speedup 1.0000x reference)
//
#include <hip/hip_runtime.h>
#include <hip/hip_bf16.h>

namespace {
constexpr int NODES = 100000;
constexpr int EMBD  = 128;
constexpr int BATCH = 1024;
constexpr int BN = 32;     // N-tile per block (100000 % 32 == 0)
constexpr int BM = 128;    // M-tile per block = 4 waves * 32 rows
}

typedef __attribute__((ext_vector_type(8))) short bf16x8_t;
typedef __attribute__((ext_vector_type(4))) float f32x4_t;

__device__ __forceinline__ short f2bf(float f) {
    __hip_bfloat16 h = __float2bfloat16(f);
    short s;
    __builtin_memcpy(&s, &h, 2);
    return s;
}

// Kernel 1: combined[b][k] = emb[subj[b]][k] * rels[rel[b]][k], stored bf16.
__global__ void combine_kernel(const int* __restrict__ subj,
                               const int* __restrict__ rel,
                               const float* __restrict__ emb,
                               const float* __restrict__ rels,
                               short* __restrict__ out) {
    const int b = blockIdx.x;
    const int t = threadIdx.x;
    const int s = subj[b];
    const int r = rel[b];
    const float v = emb[s * EMBD + t] * rels[r * EMBD + t];
    out[b * EMBD + t] = f2bf(v);
}

// Kernel 2: C[m][n] = sum_k A[m][k] * B[n][k]   (B^T GEMM)
// A: combined bf16 [BATCH][EMBD], B: embeddings f32 [NODES][EMBD]
// Block: 256 threads = 4 waves; wave w owns rows [bm*128 + w*32, +32), cols [bn*32, +32).
// No LDS: operands are L2/L3-resident; fp32 B converted to bf16 in-register.
__global__ __launch_bounds__(256) void distmult_kernel(
        const short* __restrict__ A,
        const float* __restrict__ B,
        float* __restrict__ C) {
    const int bn  = blockIdx.x;            // 0..3124
    const int bm  = blockIdx.y;            // 0..7
    const int tid = (int)threadIdx.x;
    const int w   = tid >> 6;
    const int l   = tid & 63;
    const int fr  = l & 15;                // row within 16 (A) / col within 16 (B, C)
    const int fq  = l >> 4;                // 0..3 lane group

    const int arow0 = bm * BM + w * 32;    // wave's first output row
    const int ncol0 = bn * BN;             // block's first output col

    // A fragments: a[mi][kk] — lane reads A[arow0 + mi*16 + fr][kk*32 + fq*8 .. +8]
    bf16x8_t a[2][4];
#pragma unroll
    for (int mi = 0; mi < 2; ++mi) {
        const short* p = A + (arow0 + mi * 16 + fr) * EMBD + fq * 8;
#pragma unroll
        for (int kk = 0; kk < 4; ++kk)
            a[mi][kk] = *reinterpret_cast<const bf16x8_t*>(p + kk * 32);
    }

    // B fragments from fp32 embeddings, converted to bf16 in-register.
    bf16x8_t bv[2][4];
#pragma unroll
    for (int ni = 0; ni < 2; ++ni) {
        const float* p = B + (ncol0 + ni * 16 + fr) * EMBD + fq * 8;
#pragma unroll
        for (int kk = 0; kk < 4; ++kk) {
            f32x4_t lo = *reinterpret_cast<const f32x4_t*>(p + kk * 32);
            f32x4_t hi = *reinterpret_cast<const f32x4_t*>(p + kk * 32 + 4);
            bf16x8_t t;
#pragma unroll
            for (int j = 0; j < 4; ++j) { t[j] = f2bf(lo[j]); t[4 + j] = f2bf(hi[j]); }
            bv[ni][kk] = t;
        }
    }

    f32x4_t acc[2][2] = {};
#pragma unroll
    for (int kk = 0; kk < 4; ++kk)
#pragma unroll
        for (int mi = 0; mi < 2; ++mi)
#pragma unroll
            for (int ni = 0; ni < 2; ++ni)
                acc[mi][ni] = __builtin_amdgcn_mfma_f32_16x16x32_bf16(
                    a[mi][kk], bv[ni][kk], acc[mi][ni], 0, 0, 0);

    // C/D layout: col = fr, row = fq*4 + reg  (verified m89/m91)
#pragma unroll
    for (int mi = 0; mi < 2; ++mi)
#pragma unroll
        for (int ni = 0; ni < 2; ++ni) {
            const int col = ncol0 + ni * 16 + fr;
#pragma unroll
            for (int r = 0; r < 4; ++r) {
                const int row = arow0 + mi * 16 + fq * 4 + r;
                C[(size_t)row * NODES + col] = acc[mi][ni][r];
            }
        }
}

extern "C" void kernel_launch(void* const* d_in, const int* in_sizes, int n_in,
                              void* d_out, int out_size, void* d_ws, size_t ws_size,
                              hipStream_t stream) {
    const int*   subj = (const int*)d_in[0];
    const int*   rel  = (const int*)d_in[1];
    const float* emb  = (const float*)d_in[2];
    const float* rels = (const float*)d_in[3];
    float* out = (float*)d_out;
    short* combined = (short*)d_ws;   // 1024*128*2 = 256 KB

    combine_kernel<<<BATCH, EMBD, 0, stream>>>(subj, rel, emb, rels, combined);

    dim3 grid(NODES / BN, BATCH / BM);
    distmult_kernel<<<grid, 256, 0, stream>>>(combined, emb, out);
}

// Round 2
// 163.159 us; speedup vs baseline: 1.7500x; 1.7500x over previous
//
#include <hip/hip_runtime.h>
#include <hip/hip_bf16.h>

namespace {
constexpr int NODES = 100000;
constexpr int EMBD  = 128;
constexpr int BATCH = 1024;
constexpr int NSTEP = 5;      // 32-col strips per block; 3125/5 = 625 n-blocks
constexpr int BMBLK = 128;    // 4 waves * 32 rows
}

typedef __attribute__((ext_vector_type(8))) short bf16x8_t;
typedef __attribute__((ext_vector_type(4))) float f32x4_t;

__device__ __forceinline__ short f2bf(float f) {
    __hip_bfloat16 h = __float2bfloat16(f);
    short s; __builtin_memcpy(&s, &h, 2); return s;
}

// combined[b][k] = emb[subj[b]][k] * rels[rel[b]][k], bf16
__global__ void combine_kernel(const int* __restrict__ subj,
                               const int* __restrict__ rel,
                               const float* __restrict__ emb,
                               const float* __restrict__ rels,
                               short* __restrict__ out) {
    const int b = blockIdx.x;
    const int t = threadIdx.x;
    const float v = emb[(size_t)subj[b] * EMBD + t] * rels[rel[b] * EMBD + t];
    out[b * EMBD + t] = f2bf(v);
}

// embeddings f32 -> bf16, 8 elems/thread. 12.8M elems -> 6250 blocks x 256.
__global__ void cvtB_kernel(const float* __restrict__ in, short* __restrict__ out) {
    const size_t i = (size_t)(blockIdx.x * blockDim.x + threadIdx.x) * 8;
    f32x4_t lo = *reinterpret_cast<const f32x4_t*>(in + i);
    f32x4_t hi = *reinterpret_cast<const f32x4_t*>(in + i + 4);
    bf16x8_t t;
#pragma unroll
    for (int j = 0; j < 4; ++j) { t[j] = f2bf(lo[j]); t[4 + j] = f2bf(hi[j]); }
    *reinterpret_cast<bf16x8_t*>(out + i) = t;
}

// C[m][n] = sum_k A[m][k]*B[n][k].  Block: 4 waves (32 m-rows each) x 160 cols.
// Swapped-operand MFMA: acc = mfma(b_frag, a_frag) -> lane(fq,fr) reg r holds
// C[m0+mi*16+fr][n0+ni*16+fq*4+r] -> f32x4 stores along N.
template <bool BF16B>
__global__ __launch_bounds__(256) void distmult_kernel(
        const short* __restrict__ A,
        const short* __restrict__ Bbf,
        const float* __restrict__ Bf32,
        float* __restrict__ C) {
    const int nb  = blockIdx.x;            // 0..624
    const int bm  = blockIdx.y;            // 0..7
    const int tid = (int)threadIdx.x;
    const int w   = tid >> 6;
    const int l   = tid & 63;
    const int fr  = l & 15;
    const int fq  = l >> 4;

    const int m0 = bm * BMBLK + w * 32;
    const int n0 = nb * (NSTEP * 32);

    // A fragments (reused across all N-steps): 32 VGPRs
    bf16x8_t a[2][4];
#pragma unroll
    for (int mi = 0; mi < 2; ++mi) {
        const short* p = A + (m0 + mi * 16 + fr) * EMBD + fq * 8;
#pragma unroll
        for (int kk = 0; kk < 4; ++kk)
            a[mi][kk] = *reinterpret_cast<const bf16x8_t*>(p + kk * 32);
    }

    bf16x8_t breg[2][2][4];  // double-buffered B tile (bf16 path)

    auto loadB_bf16 = [&](int t, bf16x8_t (&buf)[2][4]) {
        const int nrow0 = n0 + t * 32;
#pragma unroll
        for (int ni = 0; ni < 2; ++ni) {
            const short* p = Bbf + (size_t)(nrow0 + ni * 16 + fr) * EMBD + fq * 8;
#pragma unroll
            for (int kk = 0; kk < 4; ++kk)
                buf[ni][kk] = *reinterpret_cast<const bf16x8_t*>(p + kk * 32);
        }
    };

    if constexpr (BF16B) loadB_bf16(0, breg[0]);

#pragma unroll
    for (int t = 0; t < NSTEP; ++t) {
        bf16x8_t bcur[2][4];
        if constexpr (BF16B) {
            if (t + 1 < NSTEP) loadB_bf16(t + 1, breg[(t + 1) & 1]);
        } else {
            const int nrow0 = n0 + t * 32;
#pragma unroll
            for (int ni = 0; ni < 2; ++ni) {
                const float* p = Bf32 + (size_t)(nrow0 + ni * 16 + fr) * EMBD + fq * 8;
#pragma unroll
                for (int kk = 0; kk < 4; ++kk) {
                    f32x4_t lo = *reinterpret_cast<const f32x4_t*>(p + kk * 32);
                    f32x4_t hi = *reinterpret_cast<const f32x4_t*>(p + kk * 32 + 4);
                    bf16x8_t tv;
#pragma unroll
                    for (int j = 0; j < 4; ++j) { tv[j] = f2bf(lo[j]); tv[4 + j] = f2bf(hi[j]); }
                    bcur[ni][kk] = tv;
                }
            }
        }

        f32x4_t acc[2][2] = {};
#pragma unroll
        for (int kk = 0; kk < 4; ++kk)
#pragma unroll
            for (int mi = 0; mi < 2; ++mi)
#pragma unroll
                for (int ni = 0; ni < 2; ++ni) {
                    const bf16x8_t bv = BF16B ? breg[t & 1][ni][kk] : bcur[ni][kk];
                    acc[mi][ni] = __builtin_amdgcn_mfma_f32_16x16x32_bf16(
                        bv, a[mi][kk], acc[mi][ni], 0, 0, 0);
                }

#pragma unroll
        for (int mi = 0; mi < 2; ++mi) {
            const size_t rowoff = (size_t)(m0 + mi * 16 + fr) * NODES;
#pragma unroll
            for (int ni = 0; ni < 2; ++ni) {
                const int col = n0 + t * 32 + ni * 16 + fq * 4;
                *reinterpret_cast<f32x4_t*>(C + rowoff + col) = acc[mi][ni];
            }
        }
    }
}

extern "C" void kernel_launch(void* const* d_in, const int* in_sizes, int n_in,
                              void* d_out, int out_size, void* d_ws, size_t ws_size,
                              hipStream_t stream) {
    const int*   subj = (const int*)d_in[0];
    const int*   rel  = (const int*)d_in[1];
    const float* emb  = (const float*)d_in[2];
    const float* rels = (const float*)d_in[3];
    float* out = (float*)d_out;

    short* combined = (short*)d_ws;                          // 256 KB
    const size_t combBytes = (size_t)BATCH * EMBD * 2;
    const size_t embBytes  = (size_t)NODES * EMBD * 2;       // 25.6 MB
    short* embB = (short*)((char*)d_ws + combBytes);
    const bool useBf16 = ws_size >= combBytes + embBytes;

    combine_kernel<<<BATCH, EMBD, 0, stream>>>(subj, rel, emb, rels, combined);

    dim3 grid(NODES / (NSTEP * 32), BATCH / BMBLK);          // (625, 8)
    if (useBf16) {
        cvtB_kernel<<<NODES * EMBD / 8 / 256, 256, 0, stream>>>(emb, embB);
        distmult_kernel<true><<<grid, 256, 0, stream>>>(combined, embB, emb, out);
    } else {
        distmult_kernel<false><<<grid, 256, 0, stream>>>(combined, nullptr, emb, out);
    }
}